// Round 2
// baseline (274.154 us; speedup 1.0000x reference)
//
#include <hip/hip_runtime.h>

// Batched single-qubit Rot^4 circuit, expval |<0|psi>|^2.
// Memory-bound: 12 f32 in + 1 f32 out per row -> ~218 MB @ B=4.19M.
//
// Load strategy: the natural per-thread layout (3x float4 at 48 B stride)
// spans 48 cache lines per wave per instruction. Instead each 256-thread
// block stages its 256 rows (12 KB) through LDS:
//   - global: 768 float4 loaded contiguously (1024 B/wave/instr, perfectly
//     coalesced)
//   - LDS: row stride 13 floats (gcd(13,32)=1 -> conflict-free reads:
//     lane i hits bank (13*i)%32, each bank 2 lanes/wave64 = free)
__global__ __launch_bounds__(256) void QGN_30219389895238_kernel(
    const float* __restrict__ x,   // [n, 12]
    const float* __restrict__ w,   // [24]
    float* __restrict__ out,       // [n]
    int n) {
  constexpr int ROWS = 256;
  constexpr int STRIDE = 13;
  __shared__ float lds[ROWS * STRIDE];

  const int t = threadIdx.x;
  const long long base_row = (long long)blockIdx.x * ROWS;
  const int rows = min(ROWS, n - (int)base_row);   // rows in this block
  const int nelem = rows * 12;                     // always a multiple of 4

  // ---- cooperative coalesced load: global -> LDS (padded) ----
  const float4* __restrict__ xv4 =
      reinterpret_cast<const float4*>(x + base_row * 12);
#pragma unroll
  for (int j = 0; j < 3; ++j) {
    int f = t + j * 256;          // float4 index within the block's 12 KB
    int e0 = f * 4;               // flat element index
    if (e0 < nelem) {
      float4 v = xv4[f];
      float vals[4] = {v.x, v.y, v.z, v.w};
#pragma unroll
      for (int k = 0; k < 4; ++k) {
        int e = e0 + k;
        int r = e / 12;           // magic-mul div
        int c = e - r * 12;
        lds[r * STRIDE + c] = vals[k];
      }
    }
  }
  __syncthreads();

  if (base_row + t >= n) return;  // no further barriers below

  float xv[12];
#pragma unroll
  for (int c = 0; c < 12; ++c) xv[c] = lds[t * STRIDE + c];

  // ---- circuit: 4x Rot(phi,theta,omega) on (s0,s1), start |0> ----
  float s0r = 1.0f, s0i = 0.0f, s1r = 0.0f, s1i = 0.0f;

#pragma unroll
  for (int g = 0; g < 4; ++g) {
    float phi   = w[6 * g + 0] + xv[3 * g + 0] * w[6 * g + 1];
    float theta = w[6 * g + 2] + xv[3 * g + 1] * w[6 * g + 3];
    float omega = w[6 * g + 4] + xv[3 * g + 2] * w[6 * g + 5];

    float s, c;
    __sincosf(theta * 0.5f, &s, &c);   // c=cos(theta/2), s=sin(theta/2)
    float a = 0.5f * (phi + omega);
    float b = 0.5f * (phi - omega);
    float sa, ca, sb, cb;
    __sincosf(a, &sa, &ca);            // ea = e^{-ia} = (ca, -sa)
    __sincosf(b, &sb, &cb);            // eb = e^{+ib} = (cb, +sb)

    // m00 = ea*c; m01 = -eb*s; m10 = conj(eb)*s; m11 = conj(ea)*c
    float m00r =  ca * c, m00i = -sa * c;
    float m01r = -cb * s, m01i = -sb * s;
    float m10r =  cb * s, m10i = -sb * s;
    float m11r =  ca * c, m11i =  sa * c;

    float n0r = m00r * s0r - m00i * s0i + m01r * s1r - m01i * s1i;
    float n0i = m00r * s0i + m00i * s0r + m01r * s1i + m01i * s1r;
    float n1r = m10r * s0r - m10i * s0i + m11r * s1r - m11i * s1i;
    float n1i = m10r * s0i + m10i * s0r + m11r * s1i + m11i * s1r;
    s0r = n0r; s0i = n0i; s1r = n1r; s1i = n1i;
  }

  out[base_row + t] = s0r * s0r + s0i * s0i;
}

extern "C" void kernel_launch(void* const* d_in, const int* in_sizes, int n_in,
                              void* d_out, int out_size, void* d_ws, size_t ws_size,
                              hipStream_t stream) {
  const float* x = (const float*)d_in[0];  // [B,12] fp32
  const float* w = (const float*)d_in[1];  // [24]   fp32
  float* out = (float*)d_out;              // [B]    fp32
  int n = in_sizes[0] / 12;
  int block = 256;
  int grid = (n + block - 1) / block;
  QGN_30219389895238_kernel<<<grid, block, 0, stream>>>(x, w, out, n);
}